// Round 1
// baseline (27.648 us; speedup 1.0000x reference)
//
#include <hip/hip_runtime.h>

#define BB 16
#define QQ 200
#define NN 200
#define CC 64
#define TT 100
#define GG 50
#define SS 4
#define EE (GG*SS)   // 200

// Kernel 1: per batch, compute sq[b,t] = query_indices[b, argsort(target_indices[b])[t]]
__global__ __launch_bounds__(128) void precompute_sq_kernel(
    const int* __restrict__ query_indices,   // [B,T]
    const int* __restrict__ target_indices,  // [B,T]
    int* __restrict__ sq_out)                // [B,T] (workspace)
{
    const int b = blockIdx.x;
    __shared__ int tk[TT];
    __shared__ int qi[TT];
    __shared__ int sq_sh[TT];
    const int tid = threadIdx.x;
    if (tid < TT) {
        tk[tid] = target_indices[b * TT + tid];
        qi[tid] = query_indices[b * TT + tid];
    }
    __syncthreads();
    if (tid < TT) {
        const int key = tk[tid];
        int rank = 0;
        #pragma unroll 4
        for (int j = 0; j < TT; ++j) {
            const int kj = tk[j];
            rank += (kj < key) || (kj == key && j < tid);  // stable argsort rank
        }
        sq_sh[rank] = qi[tid];
    }
    __syncthreads();
    if (tid < TT) sq_out[b * TT + tid] = sq_sh[tid];
}

// Kernel 2: one block per (b,q). Compute per-t row softmax stats for the T
// referenced rows, gather per-edge class probabilities, sum per group,
// broadcast-write cost to all B copies of the output.
__global__ __launch_bounds__(256) void edge_cost_kernel(
    const float* __restrict__ edges,   // [B,Q,N,C]
    const int* __restrict__ sq,        // [B,T]
    const int* __restrict__ col_ids,   // [B,G,S] = [B,E]
    const int* __restrict__ tgt,       // [B,G,S] = [B,E]
    float* __restrict__ out)           // [B,Q,B*G]
{
    const int blk = blockIdx.x;
    const int b = blk / QQ;
    const int q = blk % QQ;
    const int tid = threadIdx.x;

    __shared__ int   sq_sh[TT];
    __shared__ float mx_sh[TT];
    __shared__ float sm_sh[TT];
    __shared__ float cost_sh[GG];

    if (tid < TT) sq_sh[tid] = sq[b * TT + tid];
    __syncthreads();

    const float* base = edges + ((size_t)(b * QQ + q)) * NN * CC;

    // Step 1: row max + sumexp. 16 groups of 16 lanes; each group does one row.
    const int grp  = tid >> 4;   // 0..15
    const int lane = tid & 15;   // 0..15
    for (int t = grp; t < TT; t += 16) {
        const float4 v = reinterpret_cast<const float4*>(base + (size_t)sq_sh[t] * CC)[lane];
        float m = fmaxf(fmaxf(v.x, v.y), fmaxf(v.z, v.w));
        #pragma unroll
        for (int off = 1; off < 16; off <<= 1)
            m = fmaxf(m, __shfl_xor(m, off, 64));
        float e = __expf(v.x - m) + __expf(v.y - m) + __expf(v.z - m) + __expf(v.w - m);
        #pragma unroll
        for (int off = 1; off < 16; off <<= 1)
            e += __shfl_xor(e, off, 64);
        if (lane == 0) { mx_sh[t] = m; sm_sh[t] = e; }
    }
    __syncthreads();

    // Step 2: per-edge probability, reduce groups of S=4 via shfl.
    if (tid < EE) {
        const int t_e = col_ids[b * EE + tid];
        const int c_e = tgt[b * EE + tid];
        const float x = base[(size_t)sq_sh[t_e] * CC + c_e];
        float p = __expf(x - mx_sh[t_e]) / sm_sh[t_e];
        p += __shfl_xor(p, 1, 64);
        p += __shfl_xor(p, 2, 64);
        if ((tid & 3) == 0) cost_sh[tid >> 2] = -p;
    }
    __syncthreads();

    // Step 3: broadcast-write: out[b2, q, b*G + g] for all b2 in [0,B).
    for (int i = tid; i < BB * GG; i += 256) {
        const int b2 = i / GG;
        const int g  = i % GG;
        out[((size_t)b2 * QQ + q) * (BB * GG) + b * GG + g] = cost_sh[g];
    }
}

extern "C" void kernel_launch(void* const* d_in, const int* in_sizes, int n_in,
                              void* d_out, int out_size, void* d_ws, size_t ws_size,
                              hipStream_t stream) {
    const float* edges = (const float*)d_in[0];          // [B,Q,N,C] f32
    const int* query_indices  = (const int*)d_in[1];     // [B,T]
    const int* target_indices = (const int*)d_in[2];     // [B,T]
    const int* col_ids        = (const int*)d_in[3];     // [B,G,S]
    const int* edge_tgt       = (const int*)d_in[4];     // [B,G,S]
    float* out = (float*)d_out;                          // [B,Q,B*G]
    int* sq_ws = (int*)d_ws;                             // B*T ints

    precompute_sq_kernel<<<BB, 128, 0, stream>>>(query_indices, target_indices, sq_ws);
    edge_cost_kernel<<<BB * QQ, 256, 0, stream>>>(edges, sq_ws, col_ids, edge_tgt, out);
}